// Round 1
// baseline (32.341 us; speedup 1.0000x reference)
//
#include <hip/hip_runtime.h>
#include <cstdint>

using bfrag = __attribute__((ext_vector_type(8))) short;   // 8 bf16 = 4 VGPRs
using f32x4 = __attribute__((ext_vector_type(4))) float;   // MFMA accumulator

__device__ __forceinline__ unsigned short f2bf(float f) {
    union { float f; unsigned int u; } z; z.f = f;
    unsigned int u = z.u;
    return (unsigned short)((u + 0x7FFFu + ((u >> 16) & 1u)) >> 16);  // RNE
}
__device__ __forceinline__ float bf2f(unsigned short h) {
    union { unsigned int u; float f; } z; z.u = ((unsigned int)h) << 16;
    return z.f;
}

// ---------------------------------------------------------------------------
// Kernel A: T[i,j,c] = sum_k v[i, fm[j], k, c] * v[j, fm[i], k, c]
// Write Tbf[c][i][j] (bf16; T symmetric so [n][k] read order is fine) and
// Tdiag[i][c] (f32).  v layout: (F=256, P=16, K=16, C=2) -> v[i*512+p*32+k*2+c]
// ---------------------------------------------------------------------------
__global__ __launch_bounds__(256) void build_T(const float* __restrict__ v,
                                               const int* __restrict__ fmap,
                                               unsigned short* __restrict__ Tbf,
                                               float* __restrict__ Tdiag) {
    const int i = blockIdx.x;
    const int j = threadIdx.x;
    const int pj = fmap[j];
    const int pi = fmap[i];
    const float4* va = (const float4*)(v + i * 512 + pj * 32);
    const float4* vb = (const float4*)(v + j * 512 + pi * 32);
    float a0 = 0.f, a1 = 0.f;
#pragma unroll
    for (int q = 0; q < 8; ++q) {
        float4 A = va[q], Bq = vb[q];
        a0 += A.x * Bq.x + A.z * Bq.z;   // c = 0 (elements k*2+0)
        a1 += A.y * Bq.y + A.w * Bq.w;   // c = 1 (elements k*2+1)
    }
    Tbf[i * 256 + j]         = f2bf(a0);
    Tbf[65536 + i * 256 + j] = f2bf(a1);
    if (i == j) { Tdiag[2 * i] = a0; Tdiag[2 * i + 1] = a1; }
}

// ---------------------------------------------------------------------------
// Kernel B: per 64-row tile:
//   Y_c = X * T_c via mfma_f32_16x16x32_bf16, fused row-dot full = sum_j x*Y,
//   plus linear (x W^T + b), diag (x^2 * Tdiag), log_softmax over C=2.
// 8 waves = 2 row-groups (32 rows) x 4 col-groups (64 cols).
// x staged as bf16 in LDS, 16B-chunk XOR swizzle: chunk_phys = chunk ^ (row&7).
// ---------------------------------------------------------------------------
__global__ __launch_bounds__(512) void ffm_main(const float* __restrict__ x,
                                                const float* __restrict__ W,
                                                const float* __restrict__ bias,
                                                const unsigned short* __restrict__ Tbf,
                                                const float* __restrict__ Tdiag,
                                                float* __restrict__ out) {
    __shared__ __align__(16) unsigned short xs[64 * 256];  // 32 KB, swizzled
    __shared__ float Wld[512];
    __shared__ float Tdld[512];
    __shared__ float bld[2];
    __shared__ float fullpart[2][64][4];

    const int tid = threadIdx.x;
    const int wgrow = blockIdx.x * 64;

    // ---- stage x (fp32 global, coalesced) -> bf16 swizzled LDS ----
    {
        const int r = tid >> 3;          // 0..63
        const int cq = tid & 7;          // 0..7
        const float* gx = x + (wgrow + r) * 256;
#pragma unroll
        for (int q2 = 0; q2 < 4; ++q2) {
            const int cj = cq + 8 * q2;              // logical 8-col chunk
            const float4* g4 = (const float4*)(gx + cj * 8);
            float4 u0 = g4[0], u1 = g4[1];
            bfrag pk;
            pk[0] = (short)f2bf(u0.x); pk[1] = (short)f2bf(u0.y);
            pk[2] = (short)f2bf(u0.z); pk[3] = (short)f2bf(u0.w);
            pk[4] = (short)f2bf(u1.x); pk[5] = (short)f2bf(u1.y);
            pk[6] = (short)f2bf(u1.z); pk[7] = (short)f2bf(u1.w);
            *(bfrag*)(&xs[r * 256 + ((cj ^ (r & 7)) << 3)]) = pk;
        }
        Wld[tid]  = W[tid];        // W is (2,256) row-major = 512 floats
        Tdld[tid] = Tdiag[tid];    // 512 floats, [i][c]
        if (tid < 2) bld[tid] = bias[tid];
    }
    __syncthreads();

    const int lane = tid & 63, w = tid >> 6;
    const int rg = w >> 2;       // row-group: 0..1  (32 rows each)
    const int cg = w & 3;        // col-group: 0..3  (64 cols each)
    const int lr = lane & 15;    // M/N index within fragment
    const int lg = lane >> 4;    // k-group (8 consecutive k per lane)

    f32x4 acc[2][2][4];          // [c][mb][nf]
#pragma unroll
    for (int c = 0; c < 2; ++c)
#pragma unroll
        for (int mb = 0; mb < 2; ++mb)
#pragma unroll
            for (int nf = 0; nf < 4; ++nf)
                acc[c][mb][nf] = (f32x4){0.f, 0.f, 0.f, 0.f};

#pragma unroll
    for (int ks = 0; ks < 8; ++ks) {
        bfrag a[2];
#pragma unroll
        for (int mb = 0; mb < 2; ++mb) {
            const int r = rg * 32 + mb * 16 + lr;
            const int cj = ks * 4 + lg;
            a[mb] = *(const bfrag*)(&xs[r * 256 + ((cj ^ (r & 7)) << 3)]);
        }
        bfrag bf[2][4];
#pragma unroll
        for (int c = 0; c < 2; ++c)
#pragma unroll
            for (int nf = 0; nf < 4; ++nf) {
                const int n = cg * 64 + nf * 16 + lr;
                const int k = ks * 32 + lg * 8;
                bf[c][nf] = *(const bfrag*)(Tbf + c * 65536 + n * 256 + k);
            }
#pragma unroll
        for (int c = 0; c < 2; ++c)
#pragma unroll
            for (int mb = 0; mb < 2; ++mb)
#pragma unroll
                for (int nf = 0; nf < 4; ++nf)
                    acc[c][mb][nf] = __builtin_amdgcn_mfma_f32_16x16x32_bf16(
                        a[mb], bf[c][nf], acc[c][mb][nf], 0, 0, 0);
    }

    // ---- fused row-dot: full[b,c] partial = sum_{cols of this wave} x[b,j]*Y[b,j,c]
    // C-layout: row = (lane>>4)*4 + m (from 1st operand = x), col = lane&15 (from T)
    float part[2][2][4];
#pragma unroll
    for (int c = 0; c < 2; ++c)
#pragma unroll
        for (int mb = 0; mb < 2; ++mb)
#pragma unroll
            for (int m = 0; m < 4; ++m) part[c][mb][m] = 0.f;

#pragma unroll
    for (int mb = 0; mb < 2; ++mb)
#pragma unroll
        for (int nf = 0; nf < 4; ++nf) {
            const int col = cg * 64 + nf * 16 + lr;
#pragma unroll
            for (int m = 0; m < 4; ++m) {
                const int r = rg * 32 + mb * 16 + lg * 4 + m;
                const float xv = bf2f(
                    xs[r * 256 + ((((col >> 3) ^ (r & 7)) << 3) | (col & 7))]);
#pragma unroll
                for (int c = 0; c < 2; ++c)
                    part[c][mb][m] += acc[c][mb][nf][m] * xv;
            }
        }
#pragma unroll
    for (int d = 1; d < 16; d <<= 1)
#pragma unroll
        for (int c = 0; c < 2; ++c)
#pragma unroll
            for (int mb = 0; mb < 2; ++mb)
#pragma unroll
                for (int m = 0; m < 4; ++m)
                    part[c][mb][m] += __shfl_xor(part[c][mb][m], d, 64);

    if (lr == 0) {
#pragma unroll
        for (int c = 0; c < 2; ++c)
#pragma unroll
            for (int mb = 0; mb < 2; ++mb)
#pragma unroll
                for (int m = 0; m < 4; ++m)
                    fullpart[c][rg * 32 + mb * 16 + lg * 4 + m][cg] = part[c][mb][m];
    }
    __syncthreads();

    // ---- per-row epilogue: linear + diag + log_softmax ----
    if (tid < 256) {
        const int r = tid >> 2;     // 0..63
        const int q = tid & 3;      // j-quarter
        float lin0 = 0.f, lin1 = 0.f, dg0 = 0.f, dg1 = 0.f;
#pragma unroll
        for (int jc = 0; jc < 8; ++jc) {
            const int cj = q * 8 + jc;
            bfrag xv = *(const bfrag*)(&xs[r * 256 + ((cj ^ (r & 7)) << 3)]);
#pragma unroll
            for (int e = 0; e < 8; ++e) {
                const int j = cj * 8 + e;
                const float xf = bf2f((unsigned short)xv[e]);
                lin0 += xf * Wld[j];
                lin1 += xf * Wld[256 + j];
                const float x2 = xf * xf;
                dg0 += x2 * Tdld[2 * j];
                dg1 += x2 * Tdld[2 * j + 1];
            }
        }
#pragma unroll
        for (int d = 1; d < 4; d <<= 1) {
            lin0 += __shfl_xor(lin0, d, 64);
            lin1 += __shfl_xor(lin1, d, 64);
            dg0  += __shfl_xor(dg0, d, 64);
            dg1  += __shfl_xor(dg1, d, 64);
        }
        if (q == 0) {
            const float full0 = fullpart[0][r][0] + fullpart[0][r][1] +
                                fullpart[0][r][2] + fullpart[0][r][3];
            const float full1 = fullpart[1][r][0] + fullpart[1][r][1] +
                                fullpart[1][r][2] + fullpart[1][r][3];
            const float z0 = lin0 + bld[0] + 0.5f * (full0 - dg0);
            const float z1 = lin1 + bld[1] + 0.5f * (full1 - dg1);
            const float mz = fmaxf(z0, z1);
            const float lse = mz + logf(expf(z0 - mz) + expf(z1 - mz));
            out[(wgrow + r) * 2 + 0] = z0 - lse;
            out[(wgrow + r) * 2 + 1] = z1 - lse;
        }
    }
}

extern "C" void kernel_launch(void* const* d_in, const int* in_sizes, int n_in,
                              void* d_out, int out_size, void* d_ws, size_t ws_size,
                              hipStream_t stream) {
    const float* x    = (const float*)d_in[0];
    const int*   fmap = (const int*)d_in[1];
    const float* W    = (const float*)d_in[2];
    const float* bias = (const float*)d_in[3];
    const float* v    = (const float*)d_in[4];
    float* out = (float*)d_out;

    unsigned short* Tbf = (unsigned short*)d_ws;                   // 256 KB
    float* Tdiag = (float*)((char*)d_ws + 262144);                 // 2 KB

    build_T<<<dim3(256), dim3(256), 0, stream>>>(v, fmap, Tbf, Tdiag);
    ffm_main<<<dim3(256), dim3(512), 0, stream>>>(x, W, bias, Tbf, Tdiag, out);
}

// Round 2
// 27.469 us; speedup vs baseline: 1.1773x; 1.1773x over previous
//
#include <hip/hip_runtime.h>
#include <cstdint>

using bfrag = __attribute__((ext_vector_type(8))) short;   // 8 bf16 = 4 VGPRs
using f32x4 = __attribute__((ext_vector_type(4))) float;   // MFMA accumulator

__device__ __forceinline__ unsigned short f2bf(float f) {
    union { float f; unsigned int u; } z; z.f = f;
    unsigned int u = z.u;
    return (unsigned short)((u + 0x7FFFu + ((u >> 16) & 1u)) >> 16);  // RNE
}
__device__ __forceinline__ float bf2f(unsigned short h) {
    union { unsigned int u; float f; } z; z.u = ((unsigned int)h) << 16;
    return z.f;
}

// ---------------------------------------------------------------------------
// Kernel A: T[i,j,c] = sum_k v[i, fm[j], k, c] * v[j, fm[i], k, c]
// Write Tbf[c][i][j] (bf16; T symmetric so row-major works as B^T) and
// Tdiag[i][c] (f32).  v layout: (F=256, P=16, K=16, C=2) -> v[i*512+p*32+k*2+c]
// ---------------------------------------------------------------------------
__global__ __launch_bounds__(256) void build_T(const float* __restrict__ v,
                                               const int* __restrict__ fmap,
                                               unsigned short* __restrict__ Tbf,
                                               float* __restrict__ Tdiag) {
    const int i = blockIdx.x;
    const int j = threadIdx.x;
    const int pj = fmap[j];
    const int pi = fmap[i];
    const float4* va = (const float4*)(v + i * 512 + pj * 32);
    const float4* vb = (const float4*)(v + j * 512 + pi * 32);
    float a0 = 0.f, a1 = 0.f;
#pragma unroll
    for (int q = 0; q < 8; ++q) {
        float4 A = va[q], Bq = vb[q];
        a0 += A.x * Bq.x + A.z * Bq.z;   // c = 0 (elements k*2+0)
        a1 += A.y * Bq.y + A.w * Bq.w;   // c = 1 (elements k*2+1)
    }
    Tbf[i * 256 + j]         = f2bf(a0);
    Tbf[65536 + i * 256 + j] = f2bf(a1);
    if (i == j) { Tdiag[2 * i] = a0; Tdiag[2 * i + 1] = a1; }
}

// ---------------------------------------------------------------------------
// Kernel B: per 64-row tile:
//   Y_c = X * T_c via mfma_f32_16x16x32_bf16, fused row-dot full = sum_j x*Y,
//   plus linear (x W^T + b), diag (x^2 * Tdiag), log_softmax over C=2.
// 8 waves = pure column split: wave w owns cols [w*32, w*32+32), all 64 rows.
// => T read exactly ONCE per WG (256 KB), 32 global B-loads per wave.
// x staged as bf16 in LDS, 16B-chunk XOR swizzle: chunk_phys = chunk ^ (row&7).
// ---------------------------------------------------------------------------
__global__ __launch_bounds__(512) void ffm_main(const float* __restrict__ x,
                                                const float* __restrict__ W,
                                                const float* __restrict__ bias,
                                                const unsigned short* __restrict__ Tbf,
                                                const float* __restrict__ Tdiag,
                                                float* __restrict__ out) {
    __shared__ __align__(16) unsigned short xs[64 * 256];  // 32 KB, swizzled
    __shared__ float Wld[512];
    __shared__ float Tdld[512];
    __shared__ float bld[2];
    __shared__ float fullpart[2][64][8];

    const int tid = threadIdx.x;
    const int wgrow = blockIdx.x * 64;

    // ---- stage x (fp32 global, coalesced) -> bf16 swizzled LDS ----
    {
        const int r = tid >> 3;          // 0..63
        const int cq = tid & 7;          // 0..7
        const float* gx = x + (wgrow + r) * 256;
#pragma unroll
        for (int q2 = 0; q2 < 4; ++q2) {
            const int cj = cq + 8 * q2;              // logical 8-col chunk
            const float4* g4 = (const float4*)(gx + cj * 8);
            float4 u0 = g4[0], u1 = g4[1];
            bfrag pk;
            pk[0] = (short)f2bf(u0.x); pk[1] = (short)f2bf(u0.y);
            pk[2] = (short)f2bf(u0.z); pk[3] = (short)f2bf(u0.w);
            pk[4] = (short)f2bf(u1.x); pk[5] = (short)f2bf(u1.y);
            pk[6] = (short)f2bf(u1.z); pk[7] = (short)f2bf(u1.w);
            *(bfrag*)(&xs[r * 256 + ((cj ^ (r & 7)) << 3)]) = pk;
        }
        Wld[tid]  = W[tid];        // W is (2,256) row-major = 512 floats
        Tdld[tid] = Tdiag[tid];    // 512 floats, [i][c]
        if (tid < 2) bld[tid] = bias[tid];
    }
    __syncthreads();

    const int lane = tid & 63, cg = tid >> 6;   // cg = 0..7, 32 cols each
    const int lr = lane & 15;    // M/N index within fragment
    const int lg = lane >> 4;    // k-group (8 consecutive k per lane)

    f32x4 acc[2][4][2];          // [c][mb][nf]
#pragma unroll
    for (int c = 0; c < 2; ++c)
#pragma unroll
        for (int mb = 0; mb < 4; ++mb)
#pragma unroll
            for (int nf = 0; nf < 2; ++nf)
                acc[c][mb][nf] = (f32x4){0.f, 0.f, 0.f, 0.f};

#pragma unroll
    for (int ks = 0; ks < 8; ++ks) {
        bfrag bf[2][2];          // B-frags first: 4 global 16B loads / ks
#pragma unroll
        for (int c = 0; c < 2; ++c)
#pragma unroll
            for (int nf = 0; nf < 2; ++nf) {
                const int n = cg * 32 + nf * 16 + lr;
                const int k = ks * 32 + lg * 8;
                bf[c][nf] = *(const bfrag*)(Tbf + c * 65536 + n * 256 + k);
            }
        bfrag a[4];
#pragma unroll
        for (int mb = 0; mb < 4; ++mb) {
            const int r = mb * 16 + lr;
            const int cj = ks * 4 + lg;
            a[mb] = *(const bfrag*)(&xs[r * 256 + ((cj ^ (r & 7)) << 3)]);
        }
#pragma unroll
        for (int c = 0; c < 2; ++c)
#pragma unroll
            for (int mb = 0; mb < 4; ++mb)
#pragma unroll
                for (int nf = 0; nf < 2; ++nf)
                    acc[c][mb][nf] = __builtin_amdgcn_mfma_f32_16x16x32_bf16(
                        a[mb], bf[c][nf], acc[c][mb][nf], 0, 0, 0);
    }

    // ---- fused row-dot: full[b,c] partial = sum_{cols of this wave} x[b,j]*Y[b,j,c]
    // C-layout: row = (lane>>4)*4 + m (from 1st operand = x), col = lane&15 (from T)
    float part[2][4][4];
#pragma unroll
    for (int c = 0; c < 2; ++c)
#pragma unroll
        for (int mb = 0; mb < 4; ++mb)
#pragma unroll
            for (int m = 0; m < 4; ++m) part[c][mb][m] = 0.f;

#pragma unroll
    for (int mb = 0; mb < 4; ++mb)
#pragma unroll
        for (int nf = 0; nf < 2; ++nf) {
            const int col = cg * 32 + nf * 16 + lr;
#pragma unroll
            for (int m = 0; m < 4; ++m) {
                const int r = mb * 16 + lg * 4 + m;
                const float xv = bf2f(
                    xs[r * 256 + ((((col >> 3) ^ (r & 7)) << 3) | (col & 7))]);
#pragma unroll
                for (int c = 0; c < 2; ++c)
                    part[c][mb][m] += acc[c][mb][nf][m] * xv;
            }
        }
#pragma unroll
    for (int d = 1; d < 16; d <<= 1)
#pragma unroll
        for (int c = 0; c < 2; ++c)
#pragma unroll
            for (int mb = 0; mb < 4; ++mb)
#pragma unroll
                for (int m = 0; m < 4; ++m)
                    part[c][mb][m] += __shfl_xor(part[c][mb][m], d, 64);

    if (lr == 0) {
#pragma unroll
        for (int c = 0; c < 2; ++c)
#pragma unroll
            for (int mb = 0; mb < 4; ++mb)
#pragma unroll
                for (int m = 0; m < 4; ++m)
                    fullpart[c][mb * 16 + lg * 4 + m][cg] = part[c][mb][m];
    }
    __syncthreads();

    // ---- per-row epilogue: linear + diag + log_softmax ----
    if (tid < 256) {
        const int r = tid >> 2;     // 0..63
        const int q = tid & 3;      // j-quarter
        float lin0 = 0.f, lin1 = 0.f, dg0 = 0.f, dg1 = 0.f;
#pragma unroll
        for (int jc = 0; jc < 8; ++jc) {
            const int cj = q * 8 + jc;
            bfrag xv = *(const bfrag*)(&xs[r * 256 + ((cj ^ (r & 7)) << 3)]);
#pragma unroll
            for (int e = 0; e < 8; ++e) {
                const int j = cj * 8 + e;
                const float xf = bf2f((unsigned short)xv[e]);
                lin0 += xf * Wld[j];
                lin1 += xf * Wld[256 + j];
                const float x2 = xf * xf;
                dg0 += x2 * Tdld[2 * j];
                dg1 += x2 * Tdld[2 * j + 1];
            }
        }
        float f0 = fullpart[0][r][2 * q] + fullpart[0][r][2 * q + 1];
        float f1 = fullpart[1][r][2 * q] + fullpart[1][r][2 * q + 1];
#pragma unroll
        for (int d = 1; d < 4; d <<= 1) {
            lin0 += __shfl_xor(lin0, d, 64);
            lin1 += __shfl_xor(lin1, d, 64);
            dg0  += __shfl_xor(dg0, d, 64);
            dg1  += __shfl_xor(dg1, d, 64);
            f0   += __shfl_xor(f0, d, 64);
            f1   += __shfl_xor(f1, d, 64);
        }
        if (q == 0) {
            const float z0 = lin0 + bld[0] + 0.5f * (f0 - dg0);
            const float z1 = lin1 + bld[1] + 0.5f * (f1 - dg1);
            const float mz = fmaxf(z0, z1);
            const float lse = mz + logf(expf(z0 - mz) + expf(z1 - mz));
            out[(wgrow + r) * 2 + 0] = z0 - lse;
            out[(wgrow + r) * 2 + 1] = z1 - lse;
        }
    }
}

extern "C" void kernel_launch(void* const* d_in, const int* in_sizes, int n_in,
                              void* d_out, int out_size, void* d_ws, size_t ws_size,
                              hipStream_t stream) {
    const float* x    = (const float*)d_in[0];
    const int*   fmap = (const int*)d_in[1];
    const float* W    = (const float*)d_in[2];
    const float* bias = (const float*)d_in[3];
    const float* v    = (const float*)d_in[4];
    float* out = (float*)d_out;

    unsigned short* Tbf = (unsigned short*)d_ws;                   // 256 KB
    float* Tdiag = (float*)((char*)d_ws + 262144);                 // 2 KB

    build_T<<<dim3(256), dim3(256), 0, stream>>>(v, fmap, Tbf, Tdiag);
    ffm_main<<<dim3(256), dim3(512), 0, stream>>>(x, W, bias, Tbf, Tdiag, out);
}